// Round 3
// baseline (102.892 us; speedup 1.0000x reference)
//
#include <hip/hip_runtime.h>
#include <math.h>

#define LENGTH   8192
#define CHANNELS 512
#define NSTATE   64
#define TCHUNK   256
#define NCHUNK   (LENGTH / TCHUNK)            /* 32 */
#define CTILE    64
#define NGRP     8                            /* state groups per block */
#define SPT      8                            /* states per thread */
#define TTILE    32
#define E_ELEMS  (NCHUNK * NSTATE * CHANNELS) /* 4 MB: E / carry buffer in ws */
#define LOG2E    1.4426950408889634f
#define DT       (1.0f / 4096.0f)

// Math (rescaled state h' = h/Bbar):  h'_t = Abar*h'_{t-1} + x_t ; y = sum_n CB_n h'_n
//   Abar_n = exp(A_n*dt), A_n = -exp(logA_n), CB_n = C_n*Bbar_n, Bbar = expm1(A*dt)*B/A
// Chunked (T=256), DIRECT-SIMULATION form:
//   pass1: E_k[n][c] = state after chunk k from h=0   (8 states/thread, Abar in SGPRs)
//   pass2: carry[k]  = Abar^T*carry[k-1] + E[k-1]     (serial over k, in place, in ws)
//   pass3: run chunk k from h=carry_k, y_t = sum_n CB_n h_n  (16 FMA/step/thread)
// T=256 (vs 128) halves E/carry HBM traffic again (32->16 MB) and halves pass2's
// serial chain. Block = 512 thr (64 ch x 8 state-groups), grid = 32*8 = 256 = 1/CU.
// LDS: pass1 Xl 64 KB; pass3 Xl+yp 128 KB (<=160). x staged once per block.

// Broadcast lane `lane`'s value to all lanes -> lands in an SGPR.
__device__ __forceinline__ float lane_bcast_f(float v, int lane) {
    return __int_as_float(__builtin_amdgcn_readlane(__float_as_int(v), lane));
}

// ---------------------------------------------------------------------------
// Pass 1: block = (chunk k, 64-ch tile); thread = (channel cl, state-group g).
// 8 h-states in VGPRs, Abar in SGPRs. x staged in LDS (64 KB). grid = 256.
// ---------------------------------------------------------------------------
__global__ __launch_bounds__(512, 2) void k_pass1(const float* __restrict__ x,
                                                  const float* __restrict__ logA,
                                                  float* __restrict__ E) {
    __shared__ float Xl[TCHUNK * CTILE];   // 64 KB
    int tid = threadIdx.x;
    int k   = blockIdx.x >> 3;
    int ct  = blockIdx.x & 7;
    int cl  = tid & 63;
    int g   = tid >> 6;                    // wave-uniform
    int c0g = ct * CTILE;

    const float* xsrc = x + (size_t)k * TCHUNK * CHANNELS + c0g;
    #pragma unroll
    for (int i = 0; i < 8; ++i) {
        int idx = (i << 9) + tid;          // 0..4095 float4 slots (256 t * 16 quads)
        int t   = idx >> 4;
        int cq  = (idx & 15) << 2;
        *(float4*)&Xl[t * CTILE + cq] = *(const float4*)(xsrc + (size_t)t * CHANNELS + cq);
    }

    int   nme = (g << 3) + (tid & 7);      // lane L computes Abar for n = g*8 + (L&7)
    float Av  = -expf(logA[nme]);
    float abv = exp2f(Av * DT * LOG2E);
    float a[SPT];
    #pragma unroll
    for (int i = 0; i < SPT; ++i) a[i] = lane_bcast_f(abv, i);

    float h[SPT];
    #pragma unroll
    for (int i = 0; i < SPT; ++i) h[i] = 0.f;

    __syncthreads();

    #pragma unroll 8
    for (int t = 0; t < TCHUNK; ++t) {
        float xv = Xl[t * CTILE + cl];
        #pragma unroll
        for (int i = 0; i < SPT; ++i) h[i] = fmaf(a[i], h[i], xv);
    }

    float* Ep = E + ((size_t)k * NSTATE + (g << 3)) * CHANNELS + c0g + cl;
    #pragma unroll
    for (int i = 0; i < SPT; ++i) Ep[(size_t)i * CHANNELS] = h[i];
}

// ---------------------------------------------------------------------------
// Pass 2: per (state n, channel c): serial carry scan over 32 chunks, in place,
// group-16 double-buffered (2 latency rounds). 64 blocks x 512 threads.
// ---------------------------------------------------------------------------
#define G2 16
__global__ __launch_bounds__(512, 1) void k_pass2(float* __restrict__ W,
                                                  const float* __restrict__ logA) {
    int gtid = blockIdx.x * 512 + threadIdx.x;
    int c = gtid & (CHANNELS - 1);
    int n = gtid >> 9;
    float A  = -expf(logA[n]);
    float aT = exp2f(A * ((float)TCHUNK * DT) * LOG2E);   // Abar^TCHUNK
    float* p = W + (size_t)n * CHANNELS + c;
    const size_t S = (size_t)NSTATE * CHANNELS;

    float e[2][G2];
    #pragma unroll
    for (int j = 0; j < G2; ++j) e[0][j] = p[(size_t)j * S];

    float hc = 0.f;
    #pragma unroll
    for (int k0 = 0; k0 < NCHUNK; k0 += G2) {
        const int cur = (k0 / G2) & 1;
        const int nxt = cur ^ 1;
        if (k0 + G2 < NCHUNK) {
            #pragma unroll
            for (int j = 0; j < G2; ++j) e[nxt][j] = p[(size_t)(k0 + G2 + j) * S];
        }
        #pragma unroll
        for (int j = 0; j < G2; ++j) {
            p[(size_t)(k0 + j) * S] = hc;
            hc = fmaf(aT, hc, e[cur][j]);
        }
    }
}

// ---------------------------------------------------------------------------
// Pass 3: block = (chunk k, 64-ch tile); thread = (cl, group g). h init =
// carry_k from ws; 256 steps of {h = a*h + x ; y_t += cb*h}. y-partials of the
// 8 groups combined via a 32-row LDS tile, flushed 8x as float4 stores.
// LDS = 64 (Xl) + 64 (yp) = 128 KB -> 1 block/CU (8 waves).
// ---------------------------------------------------------------------------
__global__ __launch_bounds__(512, 2) void k_pass3(const float* __restrict__ x,
                                                  const float* __restrict__ logA,
                                                  const float* __restrict__ Bv,
                                                  const float* __restrict__ Cv,
                                                  const float* __restrict__ W,
                                                  float* __restrict__ y) {
    __shared__ float Xl[TCHUNK * CTILE];       // 64 KB
    __shared__ float yp[NGRP][TTILE][CTILE];   // 64 KB
    int tid = threadIdx.x;
    int k   = blockIdx.x >> 3;
    int ct  = blockIdx.x & 7;
    int cl  = tid & 63;
    int g   = tid >> 6;                        // wave-uniform
    int c0g = ct * CTILE;

    const float* xsrc = x + (size_t)k * TCHUNK * CHANNELS + c0g;
    #pragma unroll
    for (int i = 0; i < 8; ++i) {
        int idx = (i << 9) + tid;
        int t   = idx >> 4;
        int cq  = (idx & 15) << 2;
        *(float4*)&Xl[t * CTILE + cq] = *(const float4*)(xsrc + (size_t)t * CHANNELS + cq);
    }

    int   nme  = (g << 3) + (tid & 7);
    float Av   = -expf(logA[nme]);
    float abv  = exp2f(Av * DT * LOG2E);
    float Bbar = expm1f(Av * DT) * Bv[nme] / Av;
    float cbv  = Cv[nme] * Bbar;

    float a[SPT], cb[SPT];
    #pragma unroll
    for (int i = 0; i < SPT; ++i) {
        a[i]  = lane_bcast_f(abv, i);
        cb[i] = lane_bcast_f(cbv, i);
    }

    const float* Wp = W + ((size_t)k * NSTATE + (g << 3)) * CHANNELS + c0g + cl;
    float h[SPT];
    #pragma unroll
    for (int i = 0; i < SPT; ++i) h[i] = Wp[(size_t)i * CHANNELS];

    __syncthreads();

    float* yg = y + (size_t)k * TCHUNK * CHANNELS + c0g;
    #pragma unroll
    for (int tt = 0; tt < TCHUNK / TTILE; ++tt) {
        #pragma unroll 4
        for (int t = 0; t < TTILE; ++t) {
            float xv = Xl[(tt * TTILE + t) * CTILE + cl];
            float y0 = 0.f, y1 = 0.f, y2 = 0.f, y3 = 0.f;
            #pragma unroll
            for (int i = 0; i < SPT; i += 4) {
                h[i]   = fmaf(a[i],   h[i],   xv);  y0 = fmaf(cb[i],   h[i],   y0);
                h[i+1] = fmaf(a[i+1], h[i+1], xv);  y1 = fmaf(cb[i+1], h[i+1], y1);
                h[i+2] = fmaf(a[i+2], h[i+2], xv);  y2 = fmaf(cb[i+2], h[i+2], y2);
                h[i+3] = fmaf(a[i+3], h[i+3], xv);  y3 = fmaf(cb[i+3], h[i+3], y3);
            }
            yp[g][t][cl] = (y0 + y1) + (y2 + y3);
        }
        __syncthreads();
        {   // 512 float4 slots (32 t * 16 quads), exactly one per thread
            int t  = tid >> 4;
            int cq = (tid & 15) << 2;
            float4 v0 = *(const float4*)&yp[0][t][cq];
            float4 v1 = *(const float4*)&yp[1][t][cq];
            float4 v2 = *(const float4*)&yp[2][t][cq];
            float4 v3 = *(const float4*)&yp[3][t][cq];
            float4 v4 = *(const float4*)&yp[4][t][cq];
            float4 v5 = *(const float4*)&yp[5][t][cq];
            float4 v6 = *(const float4*)&yp[6][t][cq];
            float4 v7 = *(const float4*)&yp[7][t][cq];
            *(float4*)(yg + (size_t)(tt * TTILE + t) * CHANNELS + cq) = make_float4(
                ((v0.x + v1.x) + (v2.x + v3.x)) + ((v4.x + v5.x) + (v6.x + v7.x)),
                ((v0.y + v1.y) + (v2.y + v3.y)) + ((v4.y + v5.y) + (v6.y + v7.y)),
                ((v0.z + v1.z) + (v2.z + v3.z)) + ((v4.z + v5.z) + (v6.z + v7.z)),
                ((v0.w + v1.w) + (v2.w + v3.w)) + ((v4.w + v5.w) + (v6.w + v7.w)));
        }
        __syncthreads();
    }
}

// ---------------------------------------------------------------------------
// Fallback (only if ws is too small): one thread per channel, full scan.
// ---------------------------------------------------------------------------
__global__ __launch_bounds__(256) void k_fallback(const float* __restrict__ x,
                                                  const float* __restrict__ logA,
                                                  const float* __restrict__ B,
                                                  const float* __restrict__ C,
                                                  float* __restrict__ y) {
    int c = blockIdx.x * blockDim.x + threadIdx.x;
    if (c >= CHANNELS) return;
    float Abar[NSTATE], CB[NSTATE], h[NSTATE];
    for (int n = 0; n < NSTATE; ++n) {
        float A    = -expf(logA[n]);
        float ab   = exp2f(A * DT * LOG2E);
        float Bbar = expm1f(A * DT) * B[n] / A;
        Abar[n] = ab;
        CB[n]   = C[n] * Bbar;
        h[n]    = 0.f;
    }
    for (int t = 0; t < LENGTH; ++t) {
        float xv = x[(size_t)t * CHANNELS + c];
        float acc = 0.f;
        for (int n = 0; n < NSTATE; ++n) {
            h[n] = fmaf(Abar[n], h[n], xv);
            acc  = fmaf(CB[n], h[n], acc);
        }
        y[(size_t)t * CHANNELS + c] = acc;
    }
}

extern "C" void kernel_launch(void* const* d_in, const int* in_sizes, int n_in,
                              void* d_out, int out_size, void* d_ws, size_t ws_size,
                              hipStream_t stream) {
    const float* x    = (const float*)d_in[0];
    const float* logA = (const float*)d_in[1];
    const float* B    = (const float*)d_in[2];
    const float* C    = (const float*)d_in[3];
    float* yout = (float*)d_out;

    if (ws_size < (size_t)E_ELEMS * sizeof(float)) {
        k_fallback<<<(CHANNELS + 255) / 256, 256, 0, stream>>>(x, logA, B, C, yout);
        return;
    }
    float* W = (float*)d_ws;   // E / carry buffer, 4 MB (ws poison happens regardless)

    k_pass1<<<NCHUNK * 8, 512, 0, stream>>>(x, logA, W);
    k_pass2<<<(NSTATE * CHANNELS) / 512, 512, 0, stream>>>(W, logA);
    k_pass3<<<NCHUNK * 8, 512, 0, stream>>>(x, logA, B, C, W, yout);
}

// Round 4
// 98.803 us; speedup vs baseline: 1.0414x; 1.0414x over previous
//
#include <hip/hip_runtime.h>
#include <math.h>

#define LENGTH   8192
#define CHANNELS 512
#define NSTATE   64
#define TCHUNK   128
#define NCHUNK   (LENGTH / TCHUNK)            /* 64 */
#define CTILE    64
#define NQ       4                            /* state quarters, 16 states each */
#define SPT      16                           /* states per thread */
#define TTILE    32
#define E_ELEMS  (NCHUNK * NSTATE * CHANNELS) /* 8 MB: E / carry buffer in ws */
#define LOG2E    1.4426950408889634f
#define DT       (1.0f / 4096.0f)

// Math (rescaled state h' = h/Bbar):  h'_t = Abar*h'_{t-1} + x_t ; y = sum_n CB_n h'_n
//   Abar_n = exp(A_n*dt), A_n = -exp(logA_n), CB_n = C_n*Bbar_n, Bbar = expm1(A*dt)*B/A
// Chunked (T=128), DIRECT-SIMULATION form (R2 geometry, proven 99.3 us):
//   pass1: E_k[n][c] = state after chunk k from h=0   (16 states/thread, Abar in SGPRs)
//   pass2: carry[k]  = Abar^T*carry[k-1] + E[k-1]     (serial over k, in place, in ws)
//   pass3: run chunk k from h=carry_k, y_t = sum_n CB_n h_n  (32 FMA/step/thread)
// R3 lesson: T=256 (1 block/CU in pass3) regressed +3.6us — >=2 blocks/CU of
// barrier-hiding beats ~16MB of L3-warm traffic. Keep T=128 / 256-thr blocks.
// Delta vs R2: y stores in pass3 are NON-TEMPORAL (y never re-read; keeps the
// 16MB y write from evicting L3-warm x / E that pass2/pass3 re-read).

typedef float __attribute__((ext_vector_type(4))) f32x4;

// Broadcast lane `lane`'s value to all lanes -> lands in an SGPR.
__device__ __forceinline__ float lane_bcast_f(float v, int lane) {
    return __int_as_float(__builtin_amdgcn_readlane(__float_as_int(v), lane));
}

// ---------------------------------------------------------------------------
// Pass 1: block = (chunk k, 64-ch tile); thread = (channel cl, state-quarter q).
// 16 h-states in VGPRs, Abar in SGPRs. x staged in LDS. grid = 64*8 = 512.
// ---------------------------------------------------------------------------
__global__ __launch_bounds__(256, 4) void k_pass1(const float* __restrict__ x,
                                                  const float* __restrict__ logA,
                                                  float* __restrict__ E) {
    __shared__ float Xl[TCHUNK * CTILE];   // 32 KB
    int tid = threadIdx.x;
    int k   = blockIdx.x >> 3;
    int ct  = blockIdx.x & 7;
    int cl  = tid & 63;
    int q   = tid >> 6;                    // wave-uniform
    int c0g = ct * CTILE;

    const float* xsrc = x + (size_t)k * TCHUNK * CHANNELS + c0g;
    #pragma unroll
    for (int i = 0; i < 8; ++i) {
        int idx = (i << 8) + tid;          // 0..2047 float4 slots (128 t * 16 quads)
        int t   = idx >> 4;
        int cq  = (idx & 15) << 2;
        *(float4*)&Xl[t * CTILE + cq] = *(const float4*)(xsrc + (size_t)t * CHANNELS + cq);
    }

    int   nme = (q << 4) + (cl & 15);      // lane L computes Abar for n = q*16 + (L&15)
    float Av  = -expf(logA[nme]);
    float abv = exp2f(Av * DT * LOG2E);
    float a[SPT];
    #pragma unroll
    for (int i = 0; i < SPT; ++i) a[i] = lane_bcast_f(abv, i);

    float h[SPT];
    #pragma unroll
    for (int i = 0; i < SPT; ++i) h[i] = 0.f;

    __syncthreads();

    #pragma unroll 8
    for (int t = 0; t < TCHUNK; ++t) {
        float xv = Xl[t * CTILE + cl];
        #pragma unroll
        for (int i = 0; i < SPT; ++i) h[i] = fmaf(a[i], h[i], xv);
    }

    float* Ep = E + ((size_t)k * NSTATE + (q << 4)) * CHANNELS + c0g + cl;
    #pragma unroll
    for (int i = 0; i < SPT; ++i) Ep[(size_t)i * CHANNELS] = h[i];
}

// ---------------------------------------------------------------------------
// Pass 2: per (state n, channel c): serial carry scan over 64 chunks, in place,
// group-16 double-buffered. n is block-uniform within a wave -> aT scalar-ish.
// ---------------------------------------------------------------------------
#define G2 16
__global__ __launch_bounds__(256, 1) void k_pass2(float* __restrict__ W,
                                                  const float* __restrict__ logA) {
    int gtid = blockIdx.x * 256 + threadIdx.x;
    int c = gtid & (CHANNELS - 1);
    int n = gtid >> 9;
    float A  = -expf(logA[n]);
    float aT = exp2f(A * ((float)TCHUNK * DT) * LOG2E);   // Abar^TCHUNK
    float* p = W + (size_t)n * CHANNELS + c;
    const size_t S = (size_t)NSTATE * CHANNELS;

    float e[2][G2];
    #pragma unroll
    for (int j = 0; j < G2; ++j) e[0][j] = p[(size_t)j * S];

    float hc = 0.f;
    #pragma unroll
    for (int k0 = 0; k0 < NCHUNK; k0 += G2) {
        const int cur = (k0 / G2) & 1;
        const int nxt = cur ^ 1;
        if (k0 + G2 < NCHUNK) {
            #pragma unroll
            for (int j = 0; j < G2; ++j) e[nxt][j] = p[(size_t)(k0 + G2 + j) * S];
        }
        #pragma unroll
        for (int j = 0; j < G2; ++j) {
            p[(size_t)(k0 + j) * S] = hc;
            hc = fmaf(aT, hc, e[cur][j]);
        }
    }
}

// ---------------------------------------------------------------------------
// Pass 3: block = (chunk k, 64-ch tile); thread = (cl, quarter q). h init =
// carry_k from ws; 128 steps of {h = a*h + x ; y_t += cb*h}. y-partials of the
// 4 quarters combined via a 32-row LDS tile, flushed 4x as nontemporal float4.
// LDS = 32 (Xl) + 32 (yp) = 64 KB -> 2 blocks/CU.
// ---------------------------------------------------------------------------
__global__ __launch_bounds__(256, 2) void k_pass3(const float* __restrict__ x,
                                                  const float* __restrict__ logA,
                                                  const float* __restrict__ Bv,
                                                  const float* __restrict__ Cv,
                                                  const float* __restrict__ W,
                                                  float* __restrict__ y) {
    __shared__ float Xl[TCHUNK * CTILE];       // 32 KB
    __shared__ float yp[NQ][TTILE][CTILE];     // 32 KB
    int tid = threadIdx.x;
    int k   = blockIdx.x >> 3;
    int ct  = blockIdx.x & 7;
    int cl  = tid & 63;
    int q   = tid >> 6;                        // wave-uniform
    int c0g = ct * CTILE;

    const float* xsrc = x + (size_t)k * TCHUNK * CHANNELS + c0g;
    #pragma unroll
    for (int i = 0; i < 8; ++i) {
        int idx = (i << 8) + tid;
        int t   = idx >> 4;
        int cq  = (idx & 15) << 2;
        *(float4*)&Xl[t * CTILE + cq] = *(const float4*)(xsrc + (size_t)t * CHANNELS + cq);
    }

    int   nme  = (q << 4) + (cl & 15);
    float Av   = -expf(logA[nme]);
    float abv  = exp2f(Av * DT * LOG2E);
    float Bbar = expm1f(Av * DT) * Bv[nme] / Av;
    float cbv  = Cv[nme] * Bbar;

    float a[SPT], cb[SPT];
    #pragma unroll
    for (int i = 0; i < SPT; ++i) {
        a[i]  = lane_bcast_f(abv, i);
        cb[i] = lane_bcast_f(cbv, i);
    }

    const float* Wp = W + ((size_t)k * NSTATE + (q << 4)) * CHANNELS + c0g + cl;
    float h[SPT];
    #pragma unroll
    for (int i = 0; i < SPT; ++i) h[i] = Wp[(size_t)i * CHANNELS];

    __syncthreads();

    float* yg = y + (size_t)k * TCHUNK * CHANNELS + c0g;
    #pragma unroll
    for (int tt = 0; tt < TCHUNK / TTILE; ++tt) {
        #pragma unroll 4
        for (int t = 0; t < TTILE; ++t) {
            float xv = Xl[(tt * TTILE + t) * CTILE + cl];
            float y0 = 0.f, y1 = 0.f, y2 = 0.f, y3 = 0.f;
            #pragma unroll
            for (int i = 0; i < SPT; i += 4) {
                h[i]   = fmaf(a[i],   h[i],   xv);  y0 = fmaf(cb[i],   h[i],   y0);
                h[i+1] = fmaf(a[i+1], h[i+1], xv);  y1 = fmaf(cb[i+1], h[i+1], y1);
                h[i+2] = fmaf(a[i+2], h[i+2], xv);  y2 = fmaf(cb[i+2], h[i+2], y2);
                h[i+3] = fmaf(a[i+3], h[i+3], xv);  y3 = fmaf(cb[i+3], h[i+3], y3);
            }
            yp[q][t][cl] = (y0 + y1) + (y2 + y3);
        }
        __syncthreads();
        #pragma unroll
        for (int r = 0; r < 2; ++r) {
            int idx = (r << 8) + tid;          // 0..511 float4 slots (32 t * 16 quads)
            int t   = idx >> 4;
            int cq  = (idx & 15) << 2;
            float4 v0 = *(const float4*)&yp[0][t][cq];
            float4 v1 = *(const float4*)&yp[1][t][cq];
            float4 v2 = *(const float4*)&yp[2][t][cq];
            float4 v3 = *(const float4*)&yp[3][t][cq];
            f32x4 out;
            out.x = (v0.x + v1.x) + (v2.x + v3.x);
            out.y = (v0.y + v1.y) + (v2.y + v3.y);
            out.z = (v0.z + v1.z) + (v2.z + v3.z);
            out.w = (v0.w + v1.w) + (v2.w + v3.w);
            __builtin_nontemporal_store(
                out, (f32x4*)(yg + (size_t)(tt * TTILE + t) * CHANNELS + cq));
        }
        __syncthreads();
    }
}

// ---------------------------------------------------------------------------
// Fallback (only if ws is too small): one thread per channel, full scan.
// ---------------------------------------------------------------------------
__global__ __launch_bounds__(256) void k_fallback(const float* __restrict__ x,
                                                  const float* __restrict__ logA,
                                                  const float* __restrict__ B,
                                                  const float* __restrict__ C,
                                                  float* __restrict__ y) {
    int c = blockIdx.x * blockDim.x + threadIdx.x;
    if (c >= CHANNELS) return;
    float Abar[NSTATE], CB[NSTATE], h[NSTATE];
    for (int n = 0; n < NSTATE; ++n) {
        float A    = -expf(logA[n]);
        float ab   = exp2f(A * DT * LOG2E);
        float Bbar = expm1f(A * DT) * B[n] / A;
        Abar[n] = ab;
        CB[n]   = C[n] * Bbar;
        h[n]    = 0.f;
    }
    for (int t = 0; t < LENGTH; ++t) {
        float xv = x[(size_t)t * CHANNELS + c];
        float acc = 0.f;
        for (int n = 0; n < NSTATE; ++n) {
            h[n] = fmaf(Abar[n], h[n], xv);
            acc  = fmaf(CB[n], h[n], acc);
        }
        y[(size_t)t * CHANNELS + c] = acc;
    }
}

extern "C" void kernel_launch(void* const* d_in, const int* in_sizes, int n_in,
                              void* d_out, int out_size, void* d_ws, size_t ws_size,
                              hipStream_t stream) {
    const float* x    = (const float*)d_in[0];
    const float* logA = (const float*)d_in[1];
    const float* B    = (const float*)d_in[2];
    const float* C    = (const float*)d_in[3];
    float* yout = (float*)d_out;

    if (ws_size < (size_t)E_ELEMS * sizeof(float)) {
        k_fallback<<<(CHANNELS + 255) / 256, 256, 0, stream>>>(x, logA, B, C, yout);
        return;
    }
    float* W = (float*)d_ws;   // E / carry buffer, 8 MB (ws poison happens regardless)

    k_pass1<<<NCHUNK * 8, 256, 0, stream>>>(x, logA, W);
    k_pass2<<<(NSTATE * CHANNELS) / 256, 256, 0, stream>>>(W, logA);
    k_pass3<<<NCHUNK * 8, 256, 0, stream>>>(x, logA, B, C, W, yout);
}